// Round 5
// baseline (782.749 us; speedup 1.0000x reference)
//
#include <hip/hip_runtime.h>
#include <cstdint>
#include <cstddef>

// ---------------------------------------------------------------------------
// B_Conv2d_ConvNN_K_N: two ConvNN-branching layers + fc1 + fc2.
//  * shuffle(L1) o unshuffle(L2) == identity; L2 shuffle folded into 1x1 store.
//  * kNN dist math bitwise-identical (contract-off, ascending-c fmaf chain,
//    (xn+snv)-2*dot); top-9 = 9 lexicographically-smallest (d,n) pairs ==
//    lax.top_k order (round-5: computed as 4 partial top-9s + exact merge).
//  * Weights pre-transposed o-contiguous -> float4 loads; dedicated ws region.
//  * fc1: r3's best config (117.6us): 256thr M128xN128, LDT=36, __bf16-cast
//    RTNE (r4's 8-wave split REGRESSED: halved W-amortization per wave).
//  * ROUND 5: the non-fc1 tail (~560us, 83%) was 1 wave/SIMD latency-bound.
//    einsum->512thr, conv1x1->1024thr(+staging once), conv3x3->512thr
//    (+staging once, halved LDS gathers), nbr->1024thr 4-way n-split w/ exact
//    lexicographic merge. Per-element fp32 chains unchanged -> absmax same.
// ---------------------------------------------------------------------------

#define DI static __device__ __forceinline__

typedef __attribute__((ext_vector_type(8))) short short8;
typedef __attribute__((ext_vector_type(4))) float f32x4;

// RTNE f32->bf16 via compiler fptrunc (== manual round-to-nearest-even trick
// for finite values; compiler lowers pairs to v_cvt_pk_bf16_f32 on gfx950).
DI unsigned short f2bf(float v) {
  return __builtin_bit_cast(unsigned short, (__bf16)v);
}
DI float bf2f(unsigned short h) {
  return (float)__builtin_bit_cast(__bf16, h);
}

// pixel_unshuffle(r=2) of x (B,3,32,32)
DI float xu1_at(const float* __restrict__ x, int b, int c, int t) {
  int h = t >> 4, w = t & 15;
  return x[(((size_t)b * 3 + (c >> 2)) * 32 + 2 * h + ((c >> 1) & 1)) * 32 + 2 * w + (c & 1)];
}

// ---------------- weight transposes ----------------------------------------
// wT*: (9,C,O) for einsum; wp*T: (CIN,O) for 1x1; wa*T: (CIN,9,O) for 3x3
__global__ __launch_bounds__(256) void k_prepw(
    const float* __restrict__ w1b, float* __restrict__ wT1,    // (9,12,16)
    const float* __restrict__ w2b, float* __restrict__ wT2,    // (9,64,32)
    const float* __restrict__ w1p, float* __restrict__ wp1T,   // (32,64)
    const float* __restrict__ w2p, float* __restrict__ wp2T,   // (64,128)
    const float* __restrict__ w1a, float* __restrict__ wa1T,   // (12,9,16)
    const float* __restrict__ w2a, float* __restrict__ wa2T)   // (64,9,32)
{
  int i = blockIdx.x * 256 + threadIdx.x;
  if (i < 1728) {
    int k = i / 192, r = i % 192, c = r >> 4, o = r & 15;
    wT1[i] = w1b[((size_t)o * 12 + c) * 9 + k];
    return;
  }
  i -= 1728;
  if (i < 18432) {
    int k = i / 2048, r = i % 2048, c = r >> 5, o = r & 31;
    wT2[i] = w2b[((size_t)o * 64 + c) * 9 + k];
    return;
  }
  i -= 18432;
  if (i < 2048) { int ic = i >> 6, o = i & 63; wp1T[i] = w1p[(size_t)o * 32 + ic]; return; }
  i -= 2048;
  if (i < 8192) { int ic = i >> 7, o = i & 127; wp2T[i] = w2p[(size_t)o * 64 + ic]; return; }
  i -= 8192;
  if (i < 1728) {
    int o = i & 15, u = i >> 4, ic = u / 9, tp = u % 9;
    wa1T[i] = w1a[((size_t)o * 12 + ic) * 9 + tp];
    return;
  }
  i -= 1728;
  if (i < 18432) {
    int o = i & 31, u = i >> 5, ic = u / 9, tp = u % 9;
    wa2T[i] = w2a[((size_t)o * 64 + ic) * 9 + tp];
  }
}

// ---------------- conv3x3: 512 thr, 1 px x OCT/2 o per thread --------------
// waT (CIN,9,OCT). og = t>>8 picks oc half; per-element (ic asc, tp asc)
// fmaf chain identical to the previous 2px version.
template <int CIN, bool GATHER, int CCTOT, int OCT>
__global__ __launch_bounds__(512) void k_conv3x3(
    const float* __restrict__ xsrc, const float* __restrict__ xu,
    const float* __restrict__ waT, const float* __restrict__ bias,
    float* __restrict__ ycat)
{
  constexpr int OPT3 = OCT / 2;
  int b = blockIdx.x;
  __shared__ float xs[CIN * 256];
  int t = threadIdx.x;
  if (GATHER) {
    for (int i = t; i < CIN * 256; i += 512) {
      int c = i >> 8, tt = i & 255;
      xs[i] = xu1_at(xsrc, b, c, tt);
    }
  } else {
    for (int i = t; i < CIN * 256; i += 512) xs[i] = xu[(size_t)b * CIN * 256 + i];
  }
  __syncthreads();
  int tt = t & 255, og = t >> 8;
  int oc0 = og * OPT3;
  int hh = tt >> 4, wc = tt & 15;
  float acc0[OPT3];
#pragma unroll
  for (int o = 0; o < OPT3; ++o) acc0[o] = bias[oc0 + o];
  bool vw0 = wc > 0, vw2 = wc < 15, vt = hh > 0, vb = hh < 15;
  bool mv[9] = {vt && vw0, vt, vt && vw2, vw0, true, vw2, vb && vw0, vb, vb && vw2};
  int tc[9];
#pragma unroll
  for (int dh = 0; dh < 3; ++dh)
#pragma unroll
    for (int dw = 0; dw < 3; ++dw) {
      int o0 = (hh + dh - 1) * 16 + (wc + dw - 1);
      tc[dh * 3 + dw] = o0 < 0 ? 0 : (o0 > 255 ? 255 : o0);
    }
#pragma unroll 2
  for (int ic = 0; ic < CIN; ++ic) {
    float xv[9];
#pragma unroll
    for (int tp = 0; tp < 9; ++tp) {
      float v = xs[ic * 256 + tc[tp]];
      xv[tp] = mv[tp] ? v : 0.f;
    }
    // chain per o: (ic ascending, tp ascending) == previous rounds' order
#pragma unroll
    for (int tp = 0; tp < 9; ++tp) {
      const float* wp = waT + ((size_t)ic * 9 + tp) * OCT + oc0;
#pragma unroll
      for (int oq = 0; oq < OPT3 / 4; ++oq) {
        float4 wv = ((const float4*)wp)[oq];
        float w4[4] = {wv.x, wv.y, wv.z, wv.w};
#pragma unroll
        for (int j = 0; j < 4; ++j)
          acc0[oq * 4 + j] = fmaf(xv[tp], w4[j], acc0[oq * 4 + j]);
      }
    }
  }
#pragma unroll
  for (int o = 0; o < OPT3; ++o)
    ycat[((size_t)b * CCTOT + oc0 + o) * 256 + tt] = fmaxf(acc0[o], 0.f);
}

// ---------------- sample prep (256 threads, LDS transpose) -----------------
template <int C, int STR, bool GATHER>
__global__ __launch_bounds__(256) void k_prep(
    const float* __restrict__ xsrc, const float* __restrict__ xu,
    const int* __restrict__ idx,
    float* __restrict__ sampT, float* __restrict__ samp_cn,
    float* __restrict__ snvg)
{
  int b = blockIdx.x, t = threadIdx.x;
  __shared__ float sph[C * 64];
  __shared__ int idxs[64];
  if (t < 64) idxs[t] = idx[t];
  __syncthreads();
  for (int i = t; i < C * 64; i += 256) {
    int c = i >> 6, n = i & 63;
    int p = idxs[n];
    sph[i] = GATHER ? xu1_at(xsrc, b, c, p) : xu[((size_t)b * C + c) * 256 + p];
  }
  __syncthreads();
  for (int i = t; i < C * 64; i += 256) samp_cn[(size_t)b * C * 64 + i] = sph[i];
  for (int i = t; i < 64 * STR; i += 256) {
    int n = i / STR, c = i % STR;
    if (c < C) sampT[(size_t)b * 64 * STR + i] = sph[c * 64 + n];
  }
  if (t < 64) {
    float s;
    {
#pragma clang fp contract(off)
      s = 0.f;
      for (int c = 0; c < C; ++c) { float v = sph[c * 64 + t]; s += v * v; }
    }
    snvg[(size_t)b * 64 + t] = s;
  }
}

// ---------------- kNN: 1024 thr; 4 n-groups x 16 + exact (d,n) merge -------
// Final top-9 = 9 lexicographically-smallest (d,n) pairs; sequential insert
// and split+merge produce the identical ordered result (d's bitwise equal).
template <int C, int STR, bool GATHER>
__global__ __launch_bounds__(1024) void k_nbr(
    const float* __restrict__ xsrc, const float* __restrict__ xu,
    const float* __restrict__ sampT, const float* __restrict__ snvg,
    int* __restrict__ nbr)  // (B,9,256)
{
  int b = blockIdx.x, t = threadIdx.x;
  int px = t & 255, g = t >> 8;  // g in [0,4): n range [g*16, g*16+16)
  __shared__ float md[4][256][9];
  __shared__ int mn_[4][256][9];
  float xcol[C];
#pragma unroll
  for (int c = 0; c < C; ++c)
    xcol[c] = GATHER ? xu1_at(xsrc, b, c, px) : xu[((size_t)b * C + c) * 256 + px];
  float xn;
  {
#pragma clang fp contract(off)
    xn = 0.f;
#pragma unroll
    for (int c = 0; c < C; ++c) xn += xcol[c] * xcol[c];
  }
  float bd[9];
  int bn[9];
#pragma unroll
  for (int i = 0; i < 9; ++i) { bd[i] = __builtin_inff(); bn[i] = 1 << 30; }

#pragma unroll 1
  for (int n = g * 16; n < g * 16 + 16; ++n) {
    const float* sp = sampT + ((size_t)b * 64 + n) * STR;  // wave-uniform
    float snvn = snvg[(size_t)b * 64 + n];
    float d;
    {
#pragma clang fp contract(off)
      float dot = 0.f;
#pragma unroll
      for (int c = 0; c < C; ++c) dot = fmaf(xcol[c], sp[c], dot);
      d = (xn + snvn) - 2.f * dot;
    }
    if (d < bd[8] || (d == bd[8] && n < bn[8])) {
      float dc = d;
      int nc = n;
#pragma unroll
      for (int i = 0; i < 9; ++i) {
        bool sw = (dc < bd[i]) || (dc == bd[i] && nc < bn[i]);
        float ob = bd[i]; int on = bn[i];
        bd[i] = sw ? dc : ob; bn[i] = sw ? nc : on;
        dc = sw ? ob : dc;   nc = sw ? on : nc;
      }
    }
  }
#pragma unroll
  for (int k = 0; k < 9; ++k) { md[g][px][k] = bd[k]; mn_[g][px][k] = bn[k]; }
  __syncthreads();
  if (g == 0) {
    float fd[9];
    int fn[9];
#pragma unroll
    for (int i = 0; i < 9; ++i) { fd[i] = __builtin_inff(); fn[i] = 1 << 30; }
#pragma unroll 1
    for (int gg = 0; gg < 4; ++gg)
#pragma unroll
      for (int k = 0; k < 9; ++k) {
        float d = md[gg][px][k];
        int n = mn_[gg][px][k];
        if (d < fd[8] || (d == fd[8] && n < fn[8])) {
          float dc = d;
          int nc = n;
#pragma unroll
          for (int i = 0; i < 9; ++i) {
            bool sw = (dc < fd[i]) || (dc == fd[i] && nc < fn[i]);
            float ob = fd[i]; int on = fn[i];
            fd[i] = sw ? dc : ob; fn[i] = sw ? nc : on;
            dc = sw ? ob : dc;   nc = sw ? on : nc;
          }
        }
      }
#pragma unroll
    for (int k = 0; k < 9; ++k) nbr[((size_t)b * 9 + k) * 256 + px] = fn[k];
  }
}

// ---------------- gather-einsum: 512 thr, 1 px x OPT o per thread ----------
template <int C, int OPT, int OTOT, int CCTOT, int OCBASE>
__global__ __launch_bounds__(512) void k_einsum(
    const float* __restrict__ samp_cn,  // (B,C,64)
    const int* __restrict__ nbr,
    const float* __restrict__ wT,       // (9,C,OTOT)
    const float* __restrict__ bb,
    float* __restrict__ ycat)
{
  int b = blockIdx.x, t = threadIdx.x;
  int tt = t & 255, og = t >> 8;
  int o0 = og * OPT;
  __shared__ float samps[C * 64];
  for (int i = t; i < C * 64; i += 512)
    samps[i] = samp_cn[(size_t)b * C * 64 + i];
  int bnA[9];
#pragma unroll
  for (int k = 0; k < 9; ++k)
    bnA[k] = nbr[((size_t)b * 9 + k) * 256 + tt];
  __syncthreads();
  float acc0[OPT];
#pragma unroll
  for (int o = 0; o < OPT; ++o) acc0[o] = bb[o0 + o];
#pragma unroll 1
  for (int k = 0; k < 9; ++k) {
    int n0 = bnA[k];
#pragma unroll 2
    for (int c = 0; c < C; ++c) {
      float sv0 = samps[c * 64 + n0];
      const float* wp = wT + ((size_t)k * C + c) * OTOT + o0;
#pragma unroll
      for (int oq = 0; oq < OPT / 4; ++oq) {
        float4 wv = ((const float4*)wp)[oq];
        float w4[4] = {wv.x, wv.y, wv.z, wv.w};
#pragma unroll
        for (int j = 0; j < 4; ++j)
          acc0[oq * 4 + j] = fmaf(sv0, w4[j], acc0[oq * 4 + j]);
      }
    }
  }
#pragma unroll
  for (int o = 0; o < OPT; ++o)
    ycat[((size_t)b * CCTOT + OCBASE + o0 + o) * 256 + tt] = fmaxf(acc0[o], 0.f);
}

// ---------------- 1x1 conv: 1024 thr, 1 px x OPT o; SHUF folds shuffle -----
// grid (256,1): input staged ONCE per b (was twice via grid.y).
template <int CIN, int OPT, int OCTOT, bool SHUF>
__global__ __launch_bounds__(1024) void k_conv1x1(
    const float* __restrict__ yin, const float* __restrict__ wpT,
    const float* __restrict__ bias, float* __restrict__ out)
{
  int b = blockIdx.x, t = threadIdx.x;
  int tt = t & 255, og = t >> 8;  // og in [0,4)
  int o0 = og * OPT;
  __shared__ float ys[CIN * 256];
  for (int i = t; i < CIN * 256; i += 1024) ys[i] = yin[(size_t)b * CIN * 256 + i];
  __syncthreads();
  float acc0[OPT];
#pragma unroll
  for (int o = 0; o < OPT; ++o) acc0[o] = bias[o0 + o];
#pragma unroll 2
  for (int ic = 0; ic < CIN; ++ic) {
    float sv0 = ys[ic * 256 + tt];
    const float* wp = wpT + (size_t)ic * OCTOT + o0;
#pragma unroll
    for (int oq = 0; oq < OPT / 4; ++oq) {
      float4 wv = ((const float4*)wp)[oq];
      float w4[4] = {wv.x, wv.y, wv.z, wv.w};
#pragma unroll
      for (int j = 0; j < 4; ++j)
        acc0[oq * 4 + j] = fmaf(sv0, w4[j], acc0[oq * 4 + j]);
    }
  }
  int h0 = tt >> 4, wc = tt & 15;
#pragma unroll
  for (int o = 0; o < OPT; ++o) {
    int ogl = o0 + o;
    if (SHUF) {
      int f0 = (ogl >> 2) * 1024 + (2 * h0 + ((ogl >> 1) & 1)) * 32 + (2 * wc + (ogl & 1));
      out[(size_t)b * 32768 + f0] = acc0[o];
    } else {
      out[((size_t)b * OCTOT + ogl) * 256 + tt] = acc0[o];
    }
  }
}

// ---------------- fc1: bf16x6 MFMA, M128xN128, reg-prefetch pipeline -------
// C = A(256x32768) * W^T(32768x1024); split-K 32; parts (32,256,1024).
// Grid (nb=8, mb=2, sb=32). r3's best config: 117.6us, MfmaUtil 37%.
__global__ __launch_bounds__(256, 2) void k_fc1(
    const float* __restrict__ A, const float* __restrict__ W,
    float* __restrict__ parts)
{
  constexpr int KTOT = 32768;
  constexpr int LDT = 36;
  __shared__ unsigned short Ah[128 * LDT], Am[128 * LDT], Al[128 * LDT];
  int t = threadIdx.x;
  int nb = blockIdx.x, mb = blockIdx.y, sb = blockIdx.z;
  int m0 = mb * 128, n0 = nb * 128, k0 = sb * 1024;
  int wave = t >> 6, lane = t & 63;
  int q = lane >> 4, m16 = lane & 15;

  f32x4 acc[8][2];
#pragma unroll
  for (int mt = 0; mt < 8; ++mt)
#pragma unroll
    for (int nt = 0; nt < 2; ++nt) acc[mt][nt] = (f32x4){0.f, 0.f, 0.f, 0.f};

  int arow = t >> 1, acol = (t & 1) * 16;
  const float* Ap = A + (size_t)(m0 + arow) * KTOT + k0 + acol;
  const float* W0 = W + (size_t)(n0 + wave * 32 + m16) * KTOT + k0 + q * 8;
  const float* W1 = W + (size_t)(n0 + wave * 32 + 16 + m16) * KTOT + k0 + q * 8;

  // prologue: fragment registers for ks=0
  float4 aR0 = *(const float4*)(Ap + 0);
  float4 aR1 = *(const float4*)(Ap + 4);
  float4 aR2 = *(const float4*)(Ap + 8);
  float4 aR3 = *(const float4*)(Ap + 12);
  float4 w0a = *(const float4*)(W0), w0b = *(const float4*)(W0 + 4);
  float4 w1a = *(const float4*)(W1), w1b = *(const float4*)(W1 + 4);

  for (int ks = 0; ks < 1024; ks += 32) {
    // prefetch next K-step into fresh regs (consumed after the MFMA phase;
    // clamped redundant load on the last iteration keeps it in-bounds)
    int ksn = (ks + 32 < 1024) ? ks + 32 : 0;
    float4 nA0 = *(const float4*)(Ap + ksn);
    float4 nA1 = *(const float4*)(Ap + ksn + 4);
    float4 nA2 = *(const float4*)(Ap + ksn + 8);
    float4 nA3 = *(const float4*)(Ap + ksn + 12);
    float4 nW0a = *(const float4*)(W0 + ksn), nW0b = *(const float4*)(W0 + ksn + 4);
    float4 nW1a = *(const float4*)(W1 + ksn), nW1b = *(const float4*)(W1 + ksn + 4);

    // W frags: convert in registers (no LDS); per-wave distinct N-columns
    short8 bh[2], bm[2], bl[2];
    {
      float wf0[8] = {w0a.x, w0a.y, w0a.z, w0a.w, w0b.x, w0b.y, w0b.z, w0b.w};
      float wf1[8] = {w1a.x, w1a.y, w1a.z, w1a.w, w1b.x, w1b.y, w1b.z, w1b.w};
#pragma unroll
      for (int j = 0; j < 8; ++j) {
        unsigned short h = f2bf(wf0[j]); float r1 = wf0[j] - bf2f(h);
        unsigned short m = f2bf(r1);
        bh[0][j] = (short)h; bm[0][j] = (short)m; bl[0][j] = (short)f2bf(r1 - bf2f(m));
        h = f2bf(wf1[j]); r1 = wf1[j] - bf2f(h);
        m = f2bf(r1);
        bh[1][j] = (short)h; bm[1][j] = (short)m; bl[1][j] = (short)f2bf(r1 - bf2f(m));
      }
    }
    // A frags: convert current regs -> 3 bf16 planes (16 contiguous cols)
    short8 vh0, vh1, vm0, vm1, vl0, vl1;
    {
      float av[16] = {aR0.x, aR0.y, aR0.z, aR0.w, aR1.x, aR1.y, aR1.z, aR1.w,
                      aR2.x, aR2.y, aR2.z, aR2.w, aR3.x, aR3.y, aR3.z, aR3.w};
#pragma unroll
      for (int j = 0; j < 8; ++j) {
        {
          float v = av[j];
          unsigned short h = f2bf(v); float r1 = v - bf2f(h);
          unsigned short m = f2bf(r1);
          vh0[j] = (short)h; vm0[j] = (short)m; vl0[j] = (short)f2bf(r1 - bf2f(m));
        }
        {
          float v = av[j + 8];
          unsigned short h = f2bf(v); float r1 = v - bf2f(h);
          unsigned short m = f2bf(r1);
          vh1[j] = (short)h; vm1[j] = (short)m; vl1[j] = (short)f2bf(r1 - bf2f(m));
        }
      }
    }
    __syncthreads();  // previous iteration's MFMA LDS reads complete
    {
      int off = arow * LDT + acol;
      *(short8*)&Ah[off] = vh0; *(short8*)&Ah[off + 8] = vh1;
      *(short8*)&Am[off] = vm0; *(short8*)&Am[off + 8] = vm1;
      *(short8*)&Al[off] = vl0; *(short8*)&Al[off + 8] = vl1;
    }
    __syncthreads();  // LDS planes ready
#pragma unroll
    for (int mt = 0; mt < 8; ++mt) {
      int aoff = (mt * 16 + m16) * LDT + q * 8;
      short8 ah = *(const short8*)&Ah[aoff];
      short8 am = *(const short8*)&Am[aoff];
      short8 al = *(const short8*)&Al[aoff];
#pragma unroll
      for (int nt = 0; nt < 2; ++nt) {
        acc[mt][nt] = __builtin_amdgcn_mfma_f32_16x16x32_bf16(al, bh[nt], acc[mt][nt], 0, 0, 0);
        acc[mt][nt] = __builtin_amdgcn_mfma_f32_16x16x32_bf16(am, bm[nt], acc[mt][nt], 0, 0, 0);
        acc[mt][nt] = __builtin_amdgcn_mfma_f32_16x16x32_bf16(ah, bl[nt], acc[mt][nt], 0, 0, 0);
        acc[mt][nt] = __builtin_amdgcn_mfma_f32_16x16x32_bf16(am, bh[nt], acc[mt][nt], 0, 0, 0);
        acc[mt][nt] = __builtin_amdgcn_mfma_f32_16x16x32_bf16(ah, bm[nt], acc[mt][nt], 0, 0, 0);
        acc[mt][nt] = __builtin_amdgcn_mfma_f32_16x16x32_bf16(ah, bh[nt], acc[mt][nt], 0, 0, 0);
      }
    }
    aR0 = nA0; aR1 = nA1; aR2 = nA2; aR3 = nA3;
    w0a = nW0a; w0b = nW0b; w1a = nW1a; w1b = nW1b;
  }
  // D row = q*4+reg, col = m16 (m89-verified)
  float* P = parts + (size_t)sb * 262144;
#pragma unroll
  for (int mt = 0; mt < 8; ++mt)
#pragma unroll
    for (int nt = 0; nt < 2; ++nt)
#pragma unroll
      for (int r2 = 0; r2 < 4; ++r2) {
        int m = m0 + mt * 16 + q * 4 + r2;
        int n = n0 + wave * 32 + nt * 16 + m16;
        P[(size_t)m * 1024 + n] = acc[mt][nt][r2];
      }
}

__global__ __launch_bounds__(256) void k_fc1_reduce(const float* __restrict__ parts,
                                                    const float* __restrict__ bias,
                                                    float* __restrict__ h1) {
  int i = blockIdx.x * 256 + threadIdx.x;  // 262144 total
  float s = 0.f;
#pragma unroll
  for (int sb = 0; sb < 32; ++sb) s += parts[(size_t)sb * 262144 + i];
  h1[i] = fmaxf(s + bias[i & 1023], 0.f);
}

// ---------------- fc2 ------------------------------------------------------
__global__ __launch_bounds__(256) void k_fc2(const float* __restrict__ h1,
                                             const float* __restrict__ w,
                                             const float* __restrict__ bias,
                                             float* __restrict__ out)
{
  int m = blockIdx.x, tid = threadIdx.x;
  __shared__ float hs[1024];
  __shared__ float ps[256];
  for (int i = tid; i < 1024; i += 256) hs[i] = h1[(size_t)m * 1024 + i];
  __syncthreads();
  int n = tid >> 4, sl = tid & 15;
  float p = 0.f;
  if (n < 10) {
    const float* wr = w + (size_t)n * 1024 + sl * 64;
    const float* hr = hs + sl * 64;
#pragma unroll 8
    for (int j = 0; j < 64; ++j) p = fmaf(hr[j], wr[j], p);
  }
  ps[tid] = p;
  __syncthreads();
  if (sl == 0 && n < 10) {
    float s = 0.f;
#pragma unroll
    for (int q = 0; q < 16; ++q) s += ps[n * 16 + q];
    out[(size_t)m * 10 + n] = s + bias[n];
  }
}

// ---------------------------------------------------------------------------
extern "C" void kernel_launch(void* const* d_in, const int* in_sizes, int n_in,
                              void* d_out, int out_size, void* d_ws, size_t ws_size,
                              hipStream_t stream) {
  (void)in_sizes; (void)n_in; (void)out_size; (void)ws_size;
  const float* x    = (const float*)d_in[0];
  const int*   idx1 = (const int*)d_in[1];
  const int*   idx2 = (const int*)d_in[2];
  const float* w1a  = (const float*)d_in[3];
  const float* b1a  = (const float*)d_in[4];
  const float* w1b  = (const float*)d_in[5];
  const float* b1b  = (const float*)d_in[6];
  const float* w1p  = (const float*)d_in[7];
  const float* b1p  = (const float*)d_in[8];
  const float* w2a  = (const float*)d_in[9];
  const float* b2a  = (const float*)d_in[10];
  const float* w2b  = (const float*)d_in[11];
  const float* b2b  = (const float*)d_in[12];
  const float* w2p  = (const float*)d_in[13];
  const float* b2p  = (const float*)d_in[14];
  const float* fc1w = (const float*)d_in[15];
  const float* fc1b = (const float*)d_in[16];
  const float* fc2w = (const float*)d_in[17];
  const float* fc2b = (const float*)d_in[18];

  // ws layout (floats); total 18,874,368 = 75.5 MB. Liveness (race-checked):
  //  phase1(L1): xu2 W, ycat1 RW | phase2(L2): xu2 R, ycat2 RW, hshuf W
  //  phase3(fc): parts RW (0..8.39M), h1, hshuf R
  //  weights @8,388,608..8,439,168: written only by k_prepw, read through
  //  conv1x1 L2; overlaps NOTHING (ycat2 ends exactly at 8,388,608).
  float* ws    = (float*)d_ws;
  float* xu2   = ws + 0;          // (B,64,256) = 4,194,304
  float* ycat1 = ws + 4194304;    // (B,32,256) = 2,097,152; phase-1 only
  float* ycat2 = ws + 4194304;    // (B,64,256) = 4,194,304; aliases dead ycat1
  float* WGT   = ws + 8388608;    // 50,560 weights, dedicated
  float* wT1   = WGT + 0;         // (9,12,16) =  1,728
  float* wT2   = WGT + 1728;      // (9,64,32) = 18,432
  float* wp1T  = WGT + 20160;     // (32,64)   =  2,048
  float* wp2T  = WGT + 22208;     // (64,128)  =  8,192
  float* wa1T  = WGT + 30400;     // (12,9,16) =  1,728
  float* wa2T  = WGT + 32128;     // (64,9,32) = 18,432  (ends 8,439,168)
  float* h1    = ws + 8650752;    // (256,1024) = 262,144 (ends 8,912,896)
  float* hshuf = ws + 10485760;   // (B,32768) = 8,388,608 (ends 18,874,368)
  // prep arrays alias hshuf's slot (all dead before conv1x1 L2 writes it):
  float* H        = ws + 10485760;
  int*   nbr      = (int*)(H + 0);       // (B,9,256) = 589,824
  float* sampT1   = H + 589824;          // (B,64,16) = 262,144
  float* snv1     = H + 851968;          // (B,64)    =  16,384
  float* sampT2   = H + 868352;          // (B,64,64) = 1,048,576
  float* snv2     = H + 1916928;         // (B,64)    =  16,384
  float* samp_cn1 = H + 1933312;         // (B,12,64) = 196,608
  float* samp_cn2 = H + 2129920;         // (B,64,64) = 1,048,576 (ends 3,178,496)
  float* parts = ws + 0;          // (32,256,1024) = 8,388,608; phase-3 only
  float* out   = (float*)d_out;

  // ---- prep (50,560 elements) ----
  k_prepw<<<198, 256, 0, stream>>>(w1b, wT1, w2b, wT2, w1p, wp1T, w2p, wp2T, w1a, wa1T, w2a, wa2T);
  // ---- layer 1 ----
  k_conv3x3<12, true, 32, 16><<<256, 512, 0, stream>>>(x, nullptr, wa1T, b1a, ycat1);
  k_prep<12, 16, true><<<256, 256, 0, stream>>>(x, nullptr, idx1, sampT1, samp_cn1, snv1);
  k_nbr<12, 16, true><<<256, 1024, 0, stream>>>(x, nullptr, sampT1, snv1, nbr);
  k_einsum<12, 8, 16, 32, 16><<<256, 512, 0, stream>>>(samp_cn1, nbr, wT1, b1b, ycat1);
  k_conv1x1<32, 16, 64, false><<<256, 1024, 0, stream>>>(ycat1, wp1T, b1p, xu2);
  // ---- layer 2 ----
  k_conv3x3<64, false, 64, 32><<<256, 512, 0, stream>>>(nullptr, xu2, wa2T, b2a, ycat2);
  k_prep<64, 64, false><<<256, 256, 0, stream>>>(nullptr, xu2, idx2, sampT2, samp_cn2, snv2);
  k_nbr<64, 64, false><<<256, 1024, 0, stream>>>(nullptr, xu2, sampT2, snv2, nbr);
  k_einsum<64, 16, 32, 64, 32><<<256, 512, 0, stream>>>(samp_cn2, nbr, wT2, b2b, ycat2);
  k_conv1x1<64, 32, 128, true><<<256, 1024, 0, stream>>>(ycat2, wp2T, b2p, hshuf);
  // ---- fc1 (bf16x6 MFMA, M128 tiles, split-K 32) + fc2 ----
  k_fc1<<<dim3(8, 2, 32), 256, 0, stream>>>(hshuf, fc1w, parts);
  k_fc1_reduce<<<1024, 256, 0, stream>>>(parts, fc1b, h1);
  k_fc2<<<256, 256, 0, stream>>>(h1, fc2w, fc2b, out);
}

// Round 7
// 648.161 us; speedup vs baseline: 1.2076x; 1.2076x over previous
//
#include <hip/hip_runtime.h>
#include <cstdint>
#include <cstddef>

// ---------------------------------------------------------------------------
// B_Conv2d_ConvNN_K_N: two ConvNN-branching layers + fc1 + fc2.
//  * shuffle(L1) o unshuffle(L2) == identity; L2 shuffle folded into 1x1 store.
//  * kNN dist math bitwise-identical (contract-off, ascending-c fmaf chain,
//    (xn+snv)-2*dot); stable insert == lax.top_k order.
//  * Weights pre-transposed o-contiguous -> float4 loads; dedicated ws region.
//  * fc1: r3's best config (117.6us): 256thr M128xN128, LDT=36, __bf16-cast
//    RTNE. conv3x3/conv1x1: r3 bytes (r5's 1-px conv3x3 regressed 3.5x:
//    86% stall, reverted).
//  * ROUND 7 == ROUND 6 RESUBMIT (container failed twice; kernel never ran):
//    tail is dispatch-overhead + inter-kernel-roundtrip bound (r5: intra-
//    kernel TLP changes were net 0). FUSE prep+nbr+einsum -> k_knn
//    (per layer): samples/snv/top9 all stay in LDS; 14 -> 10 dispatches;
//    sampT/snv/samp_cn/nbr HBM round-trips eliminated. All fp32 chains
//    bitwise-identical -> absmax unchanged.
// ---------------------------------------------------------------------------

#define DI static __device__ __forceinline__

typedef __attribute__((ext_vector_type(8))) short short8;
typedef __attribute__((ext_vector_type(4))) float f32x4;

// RTNE f32->bf16 via compiler fptrunc (== manual round-to-nearest-even trick
// for finite values; compiler lowers pairs to v_cvt_pk_bf16_f32 on gfx950).
DI unsigned short f2bf(float v) {
  return __builtin_bit_cast(unsigned short, (__bf16)v);
}
DI float bf2f(unsigned short h) {
  return (float)__builtin_bit_cast(__bf16, h);
}

// pixel_unshuffle(r=2) of x (B,3,32,32)
DI float xu1_at(const float* __restrict__ x, int b, int c, int t) {
  int h = t >> 4, w = t & 15;
  return x[(((size_t)b * 3 + (c >> 2)) * 32 + 2 * h + ((c >> 1) & 1)) * 32 + 2 * w + (c & 1)];
}

// ---------------- weight transposes ----------------------------------------
// wT*: (9,C,O) for einsum; wp*T: (CIN,O) for 1x1; wa*T: (CIN,9,O) for 3x3
__global__ __launch_bounds__(256) void k_prepw(
    const float* __restrict__ w1b, float* __restrict__ wT1,    // (9,12,16)
    const float* __restrict__ w2b, float* __restrict__ wT2,    // (9,64,32)
    const float* __restrict__ w1p, float* __restrict__ wp1T,   // (32,64)
    const float* __restrict__ w2p, float* __restrict__ wp2T,   // (64,128)
    const float* __restrict__ w1a, float* __restrict__ wa1T,   // (12,9,16)
    const float* __restrict__ w2a, float* __restrict__ wa2T)   // (64,9,32)
{
  int i = blockIdx.x * 256 + threadIdx.x;
  if (i < 1728) {
    int k = i / 192, r = i % 192, c = r >> 4, o = r & 15;
    wT1[i] = w1b[((size_t)o * 12 + c) * 9 + k];
    return;
  }
  i -= 1728;
  if (i < 18432) {
    int k = i / 2048, r = i % 2048, c = r >> 5, o = r & 31;
    wT2[i] = w2b[((size_t)o * 64 + c) * 9 + k];
    return;
  }
  i -= 18432;
  if (i < 2048) { int ic = i >> 6, o = i & 63; wp1T[i] = w1p[(size_t)o * 32 + ic]; return; }
  i -= 2048;
  if (i < 8192) { int ic = i >> 7, o = i & 127; wp2T[i] = w2p[(size_t)o * 64 + ic]; return; }
  i -= 8192;
  if (i < 1728) {
    int o = i & 15, u = i >> 4, ic = u / 9, tp = u % 9;
    wa1T[i] = w1a[((size_t)o * 12 + ic) * 9 + tp];
    return;
  }
  i -= 1728;
  if (i < 18432) {
    int o = i & 31, u = i >> 5, ic = u / 9, tp = u % 9;
    wa2T[i] = w2a[((size_t)o * 64 + ic) * 9 + tp];
  }
}

// ---------------- conv3x3: 2t x 8o per thread, waT (CIN,9,OCT) -------------
template <int CIN, bool GATHER, int CCTOT, int OCT>
__global__ __launch_bounds__(256) void k_conv3x3(
    const float* __restrict__ xsrc, const float* __restrict__ xu,
    const float* __restrict__ waT, const float* __restrict__ bias,
    float* __restrict__ ycat)
{
  int b = blockIdx.x;
  int ocb = blockIdx.y * 16;
  __shared__ float xs[CIN * 256];
  int t = threadIdx.x;
  if (GATHER) {
    for (int i = t; i < CIN * 256; i += 256) {
      int c = i >> 8, tt = i & 255;
      xs[i] = xu1_at(xsrc, b, c, tt);
    }
  } else {
    for (int i = t; i < CIN * 256; i += 256) xs[i] = xu[(size_t)b * CIN * 256 + i];
  }
  __syncthreads();
  int tt = t & 127, og = t >> 7;
  int oc0 = ocb + og * 8;
  int h0 = tt >> 4, wc = tt & 15;  // t0 = tt (h0 in [0,8)), t1 = tt+128 (h0+8)
  float acc0[8], acc1[8];
#pragma unroll
  for (int o = 0; o < 8; ++o) { acc0[o] = bias[oc0 + o]; acc1[o] = acc0[o]; }
  bool vw0 = wc > 0, vw2 = wc < 15, vh0 = h0 > 0, vh7 = h0 < 7;
  bool m0v[9] = {vh0 && vw0, vh0, vh0 && vw2, vw0, true, vw2, vw0, true, vw2};
  bool m1v[9] = {vw0, true, vw2, vw0, true, vw2, vh7 && vw0, vh7, vh7 && vw2};
  int tc0[9], tc1[9];
#pragma unroll
  for (int dh = 0; dh < 3; ++dh)
#pragma unroll
    for (int dw = 0; dw < 3; ++dw) {
      int o0 = (h0 + dh - 1) * 16 + (wc + dw - 1);
      int o1 = (h0 + 8 + dh - 1) * 16 + (wc + dw - 1);
      tc0[dh * 3 + dw] = o0 < 0 ? 0 : (o0 > 255 ? 255 : o0);
      tc1[dh * 3 + dw] = o1 < 0 ? 0 : (o1 > 255 ? 255 : o1);
    }
#pragma unroll 2
  for (int ic = 0; ic < CIN; ++ic) {
    float xv0[9], xv1[9];
#pragma unroll
    for (int tp = 0; tp < 9; ++tp) {
      float v0 = xs[ic * 256 + tc0[tp]];
      float v1 = xs[ic * 256 + tc1[tp]];
      xv0[tp] = m0v[tp] ? v0 : 0.f;
      xv1[tp] = m1v[tp] ? v1 : 0.f;
    }
    // chain per o: (ic ascending, tp ascending) == previous rounds' order
#pragma unroll
    for (int tp = 0; tp < 9; ++tp) {
      const float* wp = waT + ((size_t)ic * 9 + tp) * OCT + oc0;
      float4 wA = *(const float4*)wp;
      float4 wB = *(const float4*)(wp + 4);
      float wv[8] = {wA.x, wA.y, wA.z, wA.w, wB.x, wB.y, wB.z, wB.w};
#pragma unroll
      for (int o = 0; o < 8; ++o) {
        acc0[o] = fmaf(xv0[tp], wv[o], acc0[o]);
        acc1[o] = fmaf(xv1[tp], wv[o], acc1[o]);
      }
    }
  }
#pragma unroll
  for (int o = 0; o < 8; ++o) {
    ycat[((size_t)b * CCTOT + oc0 + o) * 256 + tt] = fmaxf(acc0[o], 0.f);
    ycat[((size_t)b * CCTOT + oc0 + o) * 256 + tt + 128] = fmaxf(acc1[o], 0.f);
  }
}

// ---------------- fused kNN: sample-stage + dist/top9 + gather-einsum ------
// Replaces k_prep + k_nbr + k_einsum. All per-batch intermediates in LDS:
//  sph[C][64]  = samples (k_prep's transpose; == samp_cn values)
//  snvs[64]    = sample norms (same ascending-c chain as k_prep)
//  nbs[9][256] = top-9 indices (same insertion as k_nbr)
// Values and fp32 op chains bitwise-identical to the split kernels.
template <int C, bool GATHER, int OPT, int OTOT, int CCTOT, int OCBASE>
__global__ __launch_bounds__(256) void k_knn(
    const float* __restrict__ xsrc, const float* __restrict__ xu,
    const int* __restrict__ idx,
    const float* __restrict__ wT,  // (9,C,OTOT)
    const float* __restrict__ bb,
    float* __restrict__ ycat)
{
  int b = blockIdx.x, t = threadIdx.x;
  __shared__ float sph[C * 64];
  __shared__ float snvs[64];
  __shared__ int idxs[64];
  __shared__ int nbs[9 * 256];
  if (t < 64) idxs[t] = idx[t];
  __syncthreads();
  for (int i = t; i < C * 64; i += 256) {
    int c = i >> 6, n = i & 63;
    int p = idxs[n];
    sph[i] = GATHER ? xu1_at(xsrc, b, c, p) : xu[((size_t)b * C + c) * 256 + p];
  }
  __syncthreads();
  if (t < 64) {
    float s;
    {
#pragma clang fp contract(off)
      s = 0.f;
      for (int c = 0; c < C; ++c) { float v = sph[c * 64 + t]; s += v * v; }
    }
    snvs[t] = s;
  }
  // x column for this pixel (independent of snv)
  float xcol[C];
#pragma unroll
  for (int c = 0; c < C; ++c)
    xcol[c] = GATHER ? xu1_at(xsrc, b, c, t) : xu[((size_t)b * C + c) * 256 + t];
  float xn;
  {
#pragma clang fp contract(off)
    xn = 0.f;
#pragma unroll
    for (int c = 0; c < C; ++c) xn += xcol[c] * xcol[c];
  }
  __syncthreads();  // snvs ready
  float bd[9];
  int bn[9];
#pragma unroll
  for (int i = 0; i < 9; ++i) { bd[i] = __builtin_inff(); bn[i] = 1 << 30; }
#pragma unroll 1
  for (int n = 0; n < 64; ++n) {
    float snvn = snvs[n];
    float d;
    {
#pragma clang fp contract(off)
      float dot = 0.f;
#pragma unroll
      for (int c = 0; c < C; ++c) dot = fmaf(xcol[c], sph[c * 64 + n], dot);
      d = (xn + snvn) - 2.f * dot;
    }
    if (d < bd[8] || (d == bd[8] && n < bn[8])) {
      float dc = d;
      int nc = n;
#pragma unroll
      for (int i = 0; i < 9; ++i) {
        bool sw = (dc < bd[i]) || (dc == bd[i] && nc < bn[i]);
        float ob = bd[i]; int on = bn[i];
        bd[i] = sw ? dc : ob; bn[i] = sw ? nc : on;
        dc = sw ? ob : dc;   nc = sw ? on : nc;
      }
    }
  }
#pragma unroll
  for (int k = 0; k < 9; ++k) nbs[k * 256 + t] = bn[k];
  __syncthreads();
  // ---- einsum phase (r3 body; samps == sph) ----
  int tt = t & 127, og = t >> 7;
  int o0 = og * OPT;
  int bnA[9], bnB[9];
#pragma unroll
  for (int k = 0; k < 9; ++k) {
    bnA[k] = nbs[k * 256 + tt];
    bnB[k] = nbs[k * 256 + tt + 128];
  }
  float acc0[OPT], acc1[OPT];
#pragma unroll
  for (int o = 0; o < OPT; ++o) { acc0[o] = bb[o0 + o]; acc1[o] = acc0[o]; }
#pragma unroll 1
  for (int k = 0; k < 9; ++k) {
    int n0 = bnA[k], n1 = bnB[k];
#pragma unroll 2
    for (int c = 0; c < C; ++c) {
      float sv0 = sph[c * 64 + n0];
      float sv1 = sph[c * 64 + n1];
      const float* wp = wT + ((size_t)k * C + c) * OTOT + o0;
#pragma unroll
      for (int oq = 0; oq < OPT / 4; ++oq) {
        float4 wv = ((const float4*)wp)[oq];
        float w4[4] = {wv.x, wv.y, wv.z, wv.w};
#pragma unroll
        for (int j = 0; j < 4; ++j) {
          acc0[oq * 4 + j] = fmaf(sv0, w4[j], acc0[oq * 4 + j]);
          acc1[oq * 4 + j] = fmaf(sv1, w4[j], acc1[oq * 4 + j]);
        }
      }
    }
  }
#pragma unroll
  for (int o = 0; o < OPT; ++o) {
    ycat[((size_t)b * CCTOT + OCBASE + o0 + o) * 256 + tt] = fmaxf(acc0[o], 0.f);
    ycat[((size_t)b * CCTOT + OCBASE + o0 + o) * 256 + tt + 128] = fmaxf(acc1[o], 0.f);
  }
}

// ---------------- 1x1 conv: 2t x OPT o, wpT (CIN,OCTOT); SHUF folds shuffle
template <int CIN, int OPT, int OCTOT, bool SHUF>
__global__ __launch_bounds__(256) void k_conv1x1(
    const float* __restrict__ yin, const float* __restrict__ wpT,
    const float* __restrict__ bias, float* __restrict__ out)
{
  int b = blockIdx.x, ocb = blockIdx.y * 2 * OPT, t = threadIdx.x;
  int tt = t & 127, og = t >> 7;
  int o0 = ocb + og * OPT;
  __shared__ float ys[CIN * 256];
  for (int i = t; i < CIN * 256; i += 256) ys[i] = yin[(size_t)b * CIN * 256 + i];
  __syncthreads();
  float acc0[OPT], acc1[OPT];
#pragma unroll
  for (int o = 0; o < OPT; ++o) { acc0[o] = bias[o0 + o]; acc1[o] = acc0[o]; }
#pragma unroll 2
  for (int ic = 0; ic < CIN; ++ic) {
    float sv0 = ys[ic * 256 + tt];
    float sv1 = ys[ic * 256 + tt + 128];
    const float* wp = wpT + (size_t)ic * OCTOT + o0;
#pragma unroll
    for (int oq = 0; oq < OPT / 4; ++oq) {
      float4 wv = ((const float4*)wp)[oq];
      float w4[4] = {wv.x, wv.y, wv.z, wv.w};
#pragma unroll
      for (int j = 0; j < 4; ++j) {
        acc0[oq * 4 + j] = fmaf(sv0, w4[j], acc0[oq * 4 + j]);
        acc1[oq * 4 + j] = fmaf(sv1, w4[j], acc1[oq * 4 + j]);
      }
    }
  }
  int h0 = tt >> 4, wc = tt & 15;
#pragma unroll
  for (int o = 0; o < OPT; ++o) {
    int ogl = o0 + o;
    if (SHUF) {
      int f0 = (ogl >> 2) * 1024 + (2 * h0 + ((ogl >> 1) & 1)) * 32 + (2 * wc + (ogl & 1));
      int f1 = (ogl >> 2) * 1024 + (2 * (h0 + 8) + ((ogl >> 1) & 1)) * 32 + (2 * wc + (ogl & 1));
      out[(size_t)b * 32768 + f0] = acc0[o];
      out[(size_t)b * 32768 + f1] = acc1[o];
    } else {
      out[((size_t)b * OCTOT + ogl) * 256 + tt] = acc0[o];
      out[((size_t)b * OCTOT + ogl) * 256 + tt + 128] = acc1[o];
    }
  }
}

// ---------------- fc1: bf16x6 MFMA, M128xN128, reg-prefetch pipeline -------
// C = A(256x32768) * W^T(32768x1024); split-K 32; parts (32,256,1024).
// Grid (nb=8, mb=2, sb=32). r3's best config: 117.6us, MfmaUtil 37%.
__global__ __launch_bounds__(256, 2) void k_fc1(
    const float* __restrict__ A, const float* __restrict__ W,
    float* __restrict__ parts)
{
  constexpr int KTOT = 32768;
  constexpr int LDT = 36;
  __shared__ unsigned short Ah[128 * LDT], Am[128 * LDT], Al[128 * LDT];
  int t = threadIdx.x;
  int nb = blockIdx.x, mb = blockIdx.y, sb = blockIdx.z;
  int m0 = mb * 128, n0 = nb * 128, k0 = sb * 1024;
  int wave = t >> 6, lane = t & 63;
  int q = lane >> 4, m16 = lane & 15;

  f32x4 acc[8][2];
#pragma unroll
  for (int mt = 0; mt < 8; ++mt)
#pragma unroll
    for (int nt = 0; nt < 2; ++nt) acc[mt][nt] = (f32x4){0.f, 0.f, 0.f, 0.f};

  int arow = t >> 1, acol = (t & 1) * 16;
  const float* Ap = A + (size_t)(m0 + arow) * KTOT + k0 + acol;
  const float* W0 = W + (size_t)(n0 + wave * 32 + m16) * KTOT + k0 + q * 8;
  const float* W1 = W + (size_t)(n0 + wave * 32 + 16 + m16) * KTOT + k0 + q * 8;

  // prologue: fragment registers for ks=0
  float4 aR0 = *(const float4*)(Ap + 0);
  float4 aR1 = *(const float4*)(Ap + 4);
  float4 aR2 = *(const float4*)(Ap + 8);
  float4 aR3 = *(const float4*)(Ap + 12);
  float4 w0a = *(const float4*)(W0), w0b = *(const float4*)(W0 + 4);
  float4 w1a = *(const float4*)(W1), w1b = *(const float4*)(W1 + 4);

  for (int ks = 0; ks < 1024; ks += 32) {
    // prefetch next K-step into fresh regs (consumed after the MFMA phase;
    // clamped redundant load on the last iteration keeps it in-bounds)
    int ksn = (ks + 32 < 1024) ? ks + 32 : 0;
    float4 nA0 = *(const float4*)(Ap + ksn);
    float4 nA1 = *(const float4*)(Ap + ksn + 4);
    float4 nA2 = *(const float4*)(Ap + ksn + 8);
    float4 nA3 = *(const float4*)(Ap + ksn + 12);
    float4 nW0a = *(const float4*)(W0 + ksn), nW0b = *(const float4*)(W0 + ksn + 4);
    float4 nW1a = *(const float4*)(W1 + ksn), nW1b = *(const float4*)(W1 + ksn + 4);

    // W frags: convert in registers (no LDS); per-wave distinct N-columns
    short8 bh[2], bm[2], bl[2];
    {
      float wf0[8] = {w0a.x, w0a.y, w0a.z, w0a.w, w0b.x, w0b.y, w0b.z, w0b.w};
      float wf1[8] = {w1a.x, w1a.y, w1a.z, w1a.w, w1b.x, w1b.y, w1b.z, w1b.w};
#pragma unroll
      for (int j = 0; j < 8; ++j) {
        unsigned short h = f2bf(wf0[j]); float r1 = wf0[j] - bf2f(h);
        unsigned short m = f2bf(r1);
        bh[0][j] = (short)h; bm[0][j] = (short)m; bl[0][j] = (short)f2bf(r1 - bf2f(m));
        h = f2bf(wf1[j]); r1 = wf1[j] - bf2f(h);
        m = f2bf(r1);
        bh[1][j] = (short)h; bm[1][j] = (short)m; bl[1][j] = (short)f2bf(r1 - bf2f(m));
      }
    }
    // A frags: convert current regs -> 3 bf16 planes (16 contiguous cols)
    short8 vh0, vh1, vm0, vm1, vl0, vl1;
    {
      float av[16] = {aR0.x, aR0.y, aR0.z, aR0.w, aR1.x, aR1.y, aR1.z, aR1.w,
                      aR2.x, aR2.y, aR2.z, aR2.w, aR3.x, aR3.y, aR3.z, aR3.w};
#pragma unroll
      for (int j = 0; j < 8; ++j) {
        {
          float v = av[j];
          unsigned short h = f2bf(v); float r1 = v - bf2f(h);
          unsigned short m = f2bf(r1);
          vh0[j] = (short)h; vm0[j] = (short)m; vl0[j] = (short)f2bf(r1 - bf2f(m));
        }
        {
          float v = av[j + 8];
          unsigned short h = f2bf(v); float r1 = v - bf2f(h);
          unsigned short m = f2bf(r1);
          vh1[j] = (short)h; vm1[j] = (short)m; vl1[j] = (short)f2bf(r1 - bf2f(m));
        }
      }
    }
    __syncthreads();  // previous iteration's MFMA LDS reads complete
    {
      int off = arow * LDT + acol;
      *(short8*)&Ah[off] = vh0; *(short8*)&Ah[off + 8] = vh1;
      *(short8*)&Am[off] = vm0; *(short8*)&Am[off + 8] = vm1;
      *(short8*)&Al[off] = vl0; *(short8*)&Al[off + 8] = vl1;
    }
    __syncthreads();  // LDS planes ready
#pragma unroll
    for (int mt = 0; mt < 8; ++mt) {
      int aoff = (mt * 16 + m16) * LDT + q * 8;
      short8 ah = *(const short8*)&Ah[aoff];
      short8 am = *(const short8*)&Am[aoff];
      short8 al = *(const short8*)&Al[aoff];
#pragma unroll
      for (int nt = 0; nt < 2; ++nt) {
        acc[mt][nt] = __builtin_amdgcn_mfma_f32_16x16x32_bf16(al, bh[nt], acc[mt][nt], 0, 0, 0);
        acc[mt][nt] = __builtin_amdgcn_mfma_f32_16x16x32_bf16(am, bm[nt], acc[mt][nt], 0, 0, 0);
        acc[mt][nt] = __builtin_amdgcn_mfma_f32_16x16x32_bf16(ah, bl[nt], acc[mt][nt], 0, 0, 0);
        acc[mt][nt] = __builtin_amdgcn_mfma_f32_16x16x32_bf16(am, bh[nt], acc[mt][nt], 0, 0, 0);
        acc[mt][nt] = __builtin_amdgcn_mfma_f32_16x16x32_bf16(ah, bm[nt], acc[mt][nt], 0, 0, 0);
        acc[mt][nt] = __builtin_amdgcn_mfma_f32_16x16x32_bf16(ah, bh[nt], acc[mt][nt], 0, 0, 0);
      }
    }
    aR0 = nA0; aR1 = nA1; aR2 = nA2; aR3 = nA3;
    w0a = nW0a; w0b = nW0b; w1a = nW1a; w1b = nW1b;
  }
  // D row = q*4+reg, col = m16 (m89-verified)
  float* P = parts + (size_t)sb * 262144;
#pragma unroll
  for (int mt = 0; mt < 8; ++mt)
#pragma unroll
    for (int nt = 0; nt < 2; ++nt)
#pragma unroll
      for (int r2 = 0; r2 < 4; ++r2) {
        int m = m0 + mt * 16 + q * 4 + r2;
        int n = n0 + wave * 32 + nt * 16 + m16;
        P[(size_t)m * 1024 + n] = acc[mt][nt][r2];
      }
}

__global__ __launch_bounds__(256) void k_fc1_reduce(const float* __restrict__ parts,
                                                    const float* __restrict__ bias,
                                                    float* __restrict__ h1) {
  int i = blockIdx.x * 256 + threadIdx.x;  // 262144 total
  float s = 0.f;
#pragma unroll
  for (int sb = 0; sb < 32; ++sb) s += parts[(size_t)sb * 262144 + i];
  h1[i] = fmaxf(s + bias[i & 1023], 0.f);
}

// ---------------- fc2 ------------------------------------------------------
__global__ __launch_bounds__(256) void k_fc2(const float* __restrict__ h1,
                                             const float* __restrict__ w,
                                             const float* __restrict__ bias,
                                             float* __restrict__ out)
{
  int m = blockIdx.x, tid = threadIdx.x;
  __shared__ float hs[1024];
  __shared__ float ps[256];
  for (int i = tid; i < 1024; i += 256) hs[i] = h1[(size_t)m * 1024 + i];
  __syncthreads();
  int n = tid >> 4, sl = tid & 15;
  float p = 0.f;
  if (n < 10) {
    const float* wr = w + (size_t)n * 1024 + sl * 64;
    const float* hr = hs + sl * 64;
#pragma unroll 8
    for (int j = 0; j < 64; ++j) p = fmaf(hr[j], wr[j], p);
  }
  ps[tid] = p;
  __syncthreads();
  if (sl == 0 && n < 10) {
    float s = 0.f;
#pragma unroll
    for (int q = 0; q < 16; ++q) s += ps[n * 16 + q];
    out[(size_t)m * 10 + n] = s + bias[n];
  }
}

// ---------------------------------------------------------------------------
extern "C" void kernel_launch(void* const* d_in, const int* in_sizes, int n_in,
                              void* d_out, int out_size, void* d_ws, size_t ws_size,
                              hipStream_t stream) {
  (void)in_sizes; (void)n_in; (void)out_size; (void)ws_size;
  const float* x    = (const float*)d_in[0];
  const int*   idx1 = (const int*)d_in[1];
  const int*   idx2 = (const int*)d_in[2];
  const float* w1a  = (const float*)d_in[3];
  const float* b1a  = (const float*)d_in[4];
  const float* w1b  = (const float*)d_in[5];
  const float* b1b  = (const float*)d_in[6];
  const float* w1p  = (const float*)d_in[7];
  const float* b1p  = (const float*)d_in[8];
  const float* w2a  = (const float*)d_in[9];
  const float* b2a  = (const float*)d_in[10];
  const float* w2b  = (const float*)d_in[11];
  const float* b2b  = (const float*)d_in[12];
  const float* w2p  = (const float*)d_in[13];
  const float* b2p  = (const float*)d_in[14];
  const float* fc1w = (const float*)d_in[15];
  const float* fc1b = (const float*)d_in[16];
  const float* fc2w = (const float*)d_in[17];
  const float* fc2b = (const float*)d_in[18];

  // ws layout (floats); total 18,874,368 = 75.5 MB. Liveness (race-checked):
  //  phase1(L1): xu2 W, ycat1 RW | phase2(L2): xu2 R, ycat2 RW, hshuf W
  //  phase3(fc): parts RW (0..8.39M), h1, hshuf R
  //  weights @8,388,608..8,439,168: written only by k_prepw, read through
  //  conv1x1 L2; overlaps NOTHING (ycat2 ends exactly at 8,388,608).
  //  (kNN intermediates now live in LDS; no H region needed.)
  float* ws    = (float*)d_ws;
  float* xu2   = ws + 0;          // (B,64,256) = 4,194,304
  float* ycat1 = ws + 4194304;    // (B,32,256) = 2,097,152; phase-1 only
  float* ycat2 = ws + 4194304;    // (B,64,256) = 4,194,304; aliases dead ycat1
  float* WGT   = ws + 8388608;    // 50,560 weights, dedicated
  float* wT1   = WGT + 0;         // (9,12,16) =  1,728
  float* wT2   = WGT + 1728;      // (9,64,32) = 18,432
  float* wp1T  = WGT + 20160;     // (32,64)   =  2,048
  float* wp2T  = WGT + 22208;     // (64,128)  =  8,192
  float* wa1T  = WGT + 30400;     // (12,9,16) =  1,728
  float* wa2T  = WGT + 32128;     // (64,9,32) = 18,432  (ends 8,439,168)
  float* h1    = ws + 8650752;    // (256,1024) = 262,144 (ends 8,912,896)
  float* hshuf = ws + 10485760;   // (B,32768) = 8,388,608 (ends 18,874,368)
  float* parts = ws + 0;          // (32,256,1024) = 8,388,608; phase-3 only
  float* out   = (float*)d_out;

  // ---- prep (50,560 elements) ----
  k_prepw<<<198, 256, 0, stream>>>(w1b, wT1, w2b, wT2, w1p, wp1T, w2p, wp2T, w1a, wa1T, w2a, wa2T);
  // ---- layer 1 ----
  k_conv3x3<12, true, 32, 16><<<dim3(256, 1), 256, 0, stream>>>(x, nullptr, wa1T, b1a, ycat1);
  k_knn<12, true, 8, 16, 32, 16><<<256, 256, 0, stream>>>(x, nullptr, idx1, wT1, b1b, ycat1);
  k_conv1x1<32, 32, 64, false><<<dim3(256, 1), 256, 0, stream>>>(ycat1, wp1T, b1p, xu2);
  // ---- layer 2 ----
  k_conv3x3<64, false, 64, 32><<<dim3(256, 2), 256, 0, stream>>>(nullptr, xu2, wa2T, b2a, ycat2);
  k_knn<64, false, 16, 32, 64, 32><<<256, 256, 0, stream>>>(nullptr, xu2, idx2, wT2, b2b, ycat2);
  k_conv1x1<64, 32, 128, true><<<dim3(256, 2), 256, 0, stream>>>(ycat2, wp2T, b2p, hshuf);
  // ---- fc1 (bf16x6 MFMA, M128 tiles, split-K 32) + fc2 ----
  k_fc1<<<dim3(8, 2, 32), 256, 0, stream>>>(hshuf, fc1w, parts);
  k_fc1_reduce<<<1024, 256, 0, stream>>>(parts, fc1b, h1);
  k_fc2<<<256, 256, 0, stream>>>(h1, fc2w, fc2b, out);
}